// Round 12
// baseline (358.798 us; speedup 1.0000x reference)
//
#include <hip/hip_runtime.h>
#include <hip/hip_bf16.h>
#include <stdint.h>
#include <stddef.h>

// ---------- types ----------
typedef __attribute__((ext_vector_type(8))) short bf16x8;          // 8 bf16 in 4 VGPRs
typedef __attribute__((ext_vector_type(8))) unsigned short u16x8;  // 16B vector
typedef __attribute__((ext_vector_type(4))) float f32x4;
typedef __attribute__((ext_vector_type(16))) float f32x16;

#define MFMA16(a, b, c) __builtin_amdgcn_mfma_f32_16x16x32_bf16((a), (b), (c), 0, 0, 0)
#define MFMA32(a, b, c) __builtin_amdgcn_mfma_f32_32x32x16_bf16((a), (b), (c), 0, 0, 0)

__device__ __forceinline__ unsigned short f2b(float f) {  // f32 -> bf16 RNE
  union { float f; unsigned u; } v; v.f = f;
  unsigned r = v.u + 0x7fffu + ((v.u >> 16) & 1u);
  return (unsigned short)(r >> 16);
}
__device__ __forceinline__ float b2f(unsigned short h) {
  union { unsigned u; float f; } v; v.u = ((unsigned)h) << 16;
  return v.f;
}

__device__ __forceinline__ void gload_lds16(const void* g, void* l) {
  __builtin_amdgcn_global_load_lds((const __attribute__((address_space(1))) void*)g,
                                   (__attribute__((address_space(3))) void*)l, 16, 0, 0);
}

// ---------- fused Wq/Wk/Wv transpose+convert -> WT[n][k] (n<6144, k<4096) ----------
__global__ void k_transpose_qkv(const float* __restrict__ Wq, const float* __restrict__ Wk,
                                const float* __restrict__ Wv, unsigned short* __restrict__ out) {
  __shared__ float tile[64][65];
  const int kb = blockIdx.x * 64;
  const int nbg = blockIdx.y * 64;          // fused output row block (0..6143)
  const float* src; int srcN, nb;
  if (nbg < 4096)      { src = Wq; srcN = 4096; nb = nbg; }
  else if (nbg < 5120) { src = Wk; srcN = 1024; nb = nbg - 4096; }
  else                 { src = Wv; srcN = 1024; nb = nbg - 5120; }
  const int t = threadIdx.x;
  const int c4 = (t & 15) * 4;
  const int rr = t >> 4;
#pragma unroll
  for (int i = 0; i < 4; ++i) {
    int r = rr + i * 16;
    float4 v = *reinterpret_cast<const float4*>(src + (size_t)(kb + r) * srcN + nb + c4);
    tile[r][c4 + 0] = v.x; tile[r][c4 + 1] = v.y;
    tile[r][c4 + 2] = v.z; tile[r][c4 + 3] = v.w;
  }
  __syncthreads();
#pragma unroll
  for (int i = 0; i < 4; ++i) {
    int n = rr + i * 16;
    ushort4 w;
    w.x = f2b(tile[c4 + 0][n]); w.y = f2b(tile[c4 + 1][n]);
    w.z = f2b(tile[c4 + 2][n]); w.w = f2b(tile[c4 + 3][n]);
    *reinterpret_cast<ushort4*>(out + (size_t)(nbg + n) * 4096 + kb + c4) = w;
  }
}

// ---------- transpose + convert f32 (K x N) -> bf16 (N x K) ----------
__global__ void k_transpose_f32_bf16(const float* __restrict__ in,
                                     unsigned short* __restrict__ out,
                                     int K, int N) {
  __shared__ float tile[64][65];
  const int kb = blockIdx.x * 64;
  const int nb = blockIdx.y * 64;
  const int t = threadIdx.x;
  const int c4 = (t & 15) * 4;
  const int rr = t >> 4;
#pragma unroll
  for (int i = 0; i < 4; ++i) {
    int r = rr + i * 16;
    float4 v = *reinterpret_cast<const float4*>(in + (size_t)(kb + r) * N + nb + c4);
    tile[r][c4 + 0] = v.x; tile[r][c4 + 1] = v.y;
    tile[r][c4 + 2] = v.z; tile[r][c4 + 3] = v.w;
  }
  __syncthreads();
#pragma unroll
  for (int i = 0; i < 4; ++i) {
    int n = rr + i * 16;
    ushort4 w;
    w.x = f2b(tile[c4 + 0][n]); w.y = f2b(tile[c4 + 1][n]);
    w.z = f2b(tile[c4 + 2][n]); w.w = f2b(tile[c4 + 3][n]);
    *reinterpret_cast<ushort4*>(out + (size_t)(nb + n) * K + kb + c4) = w;
  }
}

// ---------- elementwise f32 -> bf16 ----------
__global__ void k_f32_to_bf16(const float* __restrict__ in, unsigned short* __restrict__ out) {
  size_t i = ((size_t)blockIdx.x * blockDim.x + threadIdx.x) * 4;
  float4 v = *reinterpret_cast<const float4*>(in + i);
  ushort4 w; w.x = f2b(v.x); w.y = f2b(v.y); w.z = f2b(v.z); w.w = f2b(v.w);
  *reinterpret_cast<ushort4*>(out + i) = w;
}

// ---------- GEMM v3: BK=64, double-buffered gload_lds with counted vmcnt(8) ----------
// Ledger identical to the proven R10 attention schedule: prologue stages tile 0;
// each iter stages tile t+1 into buf^1 (8 gloads in flight across the whole MFMA
// phase), gate vmcnt(8) -> tile t landed. Swizzle: rule-#21 involution.
template <bool OUT_F32>
__global__ void __launch_bounds__(256, 2)
k_gemm(const unsigned short* __restrict__ A, const unsigned short* __restrict__ Bt,
       void* __restrict__ C, int M, int N, int K) {
  __shared__ unsigned short As[2][128 * 64];
  __shared__ unsigned short Bs[2][128 * 64];
  const int nbm = M >> 7;
  const int per = ((M >> 7) * (N >> 7)) >> 3;
  const int wg  = (blockIdx.x & 7) * per + (blockIdx.x >> 3);
  const int m0 = (wg % nbm) * 128;
  const int n0 = (wg / nbm) * 128;
  const int tid = threadIdx.x;
  const int lane = tid & 63;
  const int w = tid >> 6;
  const int wr = w >> 1, wc = w & 1;
  const int cl = lane & 15, rg = lane >> 4;

  f32x4 acc[4][4] = {};

  // stage 128x64 A and B tiles of K-step T into buffer BUF (8 gloads/thread)
#define GSTAGE(T, BUF)                                                         \
  {                                                                            \
    _Pragma("unroll")                                                          \
    for (int i = 0; i < 4; ++i) {                                              \
      int c = i * 256 + tid;                                                   \
      int row = c >> 3;                                                        \
      int sc = ((c & 7) * 8) ^ ((row & 7) * 8);                                \
      gload_lds16(A + (size_t)(m0 + row) * K + (size_t)(T) * 64 + sc,          \
                  As[BUF] + c * 8);                                            \
    }                                                                          \
    _Pragma("unroll")                                                          \
    for (int i = 0; i < 4; ++i) {                                              \
      int c = i * 256 + tid;                                                   \
      int row = c >> 3;                                                        \
      int sc = ((c & 7) * 8) ^ ((row & 7) * 8);                                \
      gload_lds16(Bt + (size_t)(n0 + row) * K + (size_t)(T) * 64 + sc,         \
                  Bs[BUF] + c * 8);                                            \
    }                                                                          \
  }

  // prologue: tile 0 -> buf 0 (8 loads in flight)
  GSTAGE(0, 0)

  const int nt = K >> 6;
  for (int t = 0; t < nt; ++t) {
    const int cur = t & 1;
    const int tn = (t + 1 < nt) ? t + 1 : t;   // clamp keeps vmcnt count uniform
    // issue next tile into the other buffer (stays in flight across compute)
    GSTAGE(tn, cur ^ 1)
    // gate: tile t (8 oldest) landed; 8 newest stay in flight
    asm volatile("s_waitcnt vmcnt(8)" ::: "memory");
    __builtin_amdgcn_sched_barrier(0);
    __builtin_amdgcn_s_barrier();
    __builtin_amdgcn_sched_barrier(0);

    bf16x8 a[4][2], b[4][2];
#pragma unroll
    for (int mi = 0; mi < 4; ++mi) {
      int row = wr * 64 + mi * 16 + cl;
      int swz = (row & 7) << 4;   // byte XOR
#pragma unroll
      for (int ks = 0; ks < 2; ++ks)
        a[mi][ks] = *reinterpret_cast<const bf16x8*>(
            (const char*)As[cur] + ((row * 128 + (ks * 32 + rg * 8) * 2) ^ swz));
    }
#pragma unroll
    for (int ni = 0; ni < 4; ++ni) {
      int row = wc * 64 + ni * 16 + cl;
      int swz = (row & 7) << 4;
#pragma unroll
      for (int ks = 0; ks < 2; ++ks)
        b[ni][ks] = *reinterpret_cast<const bf16x8*>(
            (const char*)Bs[cur] + ((row * 128 + (ks * 32 + rg * 8) * 2) ^ swz));
    }
    __builtin_amdgcn_s_setprio(1);
#pragma unroll
    for (int ks = 0; ks < 2; ++ks)
#pragma unroll
      for (int mi = 0; mi < 4; ++mi)
#pragma unroll
        for (int ni = 0; ni < 4; ++ni)
          acc[mi][ni] = MFMA16(a[mi][ks], b[ni][ks], acc[mi][ni]);
    __builtin_amdgcn_s_setprio(0);

    // end barrier: all waves done reading buf cur before next iter restages it
    __builtin_amdgcn_sched_barrier(0);
    __builtin_amdgcn_s_barrier();
    __builtin_amdgcn_sched_barrier(0);
  }
#undef GSTAGE

#pragma unroll
  for (int mi = 0; mi < 4; ++mi)
#pragma unroll
    for (int ni = 0; ni < 4; ++ni) {
      int row = m0 + wr * 64 + mi * 16 + rg * 4;
      int col = n0 + wc * 64 + ni * 16 + cl;
#pragma unroll
      for (int r = 0; r < 4; ++r) {
        float v = acc[mi][ni][r];
        if (OUT_F32) ((float*)C)[(size_t)(row + r) * N + col] = v;
        else         ((unsigned short*)C)[(size_t)(row + r) * N + col] = f2b(v);
      }
    }
}

// ---------- RoPE + reshape ----------
__global__ void k_rope(const unsigned short* __restrict__ Cpre,
                       const float* __restrict__ cosb, const float* __restrict__ sinb,
                       unsigned short* __restrict__ Qr, unsigned short* __restrict__ Kr) {
  const int s = blockIdx.x;
  const int hh = blockIdx.y * 2 + (threadIdx.x >> 7);
  const int d = threadIdx.x & 127;
  const int col = (hh < 32) ? hh * 128 + d : 4096 + (hh - 32) * 128 + d;
  float t = b2f(Cpre[(size_t)s * 6144 + col]);
  const int dp = (d < 64) ? d + 64 : d - 64;
  float tp = b2f(Cpre[(size_t)s * 6144 + (col - d + dp)]);
  float rot = (d < 64) ? -tp : tp;
  float o = t * cosb[s * 128 + d] + rot * sinb[s * 128 + d];
  if (hh < 32) {
    Qr[((size_t)hh * 2048 + s) * 128 + d] = f2b(o * 0.08838834764831845f);
  } else {
    Kr[((size_t)(hh - 32) * 2048 + s) * 128 + d] = f2b(o);
  }
}

// ---------- V transpose: Cpre[S, 5120 + kv*128 + d] -> Vt[KV, DH, S] ----------
__global__ void k_transpose_v(const unsigned short* __restrict__ Cpre,
                              unsigned short* __restrict__ Vt) {
  __shared__ unsigned short tile[64][72];
  const int sb = blockIdx.x * 64;
  const int db = blockIdx.y * 64;
  const int kv = blockIdx.z;
  const int t = threadIdx.x;
#pragma unroll
  for (int i = 0; i < 2; ++i) {
    int sl = i * 32 + (t >> 3);
    int d8 = (t & 7) * 8;
    const unsigned short* src = Cpre + (size_t)(sb + sl) * 6144 + 5120 + kv * 128 + db + d8;
    ushort4 v0 = *reinterpret_cast<const ushort4*>(src);
    ushort4 v1 = *reinterpret_cast<const ushort4*>(src + 4);
    *reinterpret_cast<ushort4*>(&tile[sl][d8]) = v0;
    *reinterpret_cast<ushort4*>(&tile[sl][d8 + 4]) = v1;
  }
  __syncthreads();
#pragma unroll
  for (int i = 0; i < 2; ++i) {
    int dl = i * 32 + (t >> 3);
    int s8 = (t & 7) * 8;
    ushort4 w0, w1;
    w0.x = tile[s8 + 0][dl]; w0.y = tile[s8 + 1][dl]; w0.z = tile[s8 + 2][dl]; w0.w = tile[s8 + 3][dl];
    w1.x = tile[s8 + 4][dl]; w1.y = tile[s8 + 5][dl]; w1.z = tile[s8 + 6][dl]; w1.w = tile[s8 + 7][dl];
    unsigned short* dst = Vt + ((size_t)kv * 128 + db + dl) * 2048 + sb + s8;
    *reinterpret_cast<ushort4*>(dst) = w0;
    *reinterpret_cast<ushort4*>(dst + 4) = w1;
  }
}

// ---------- fused causal GQA flash attention (R10 known-good) ----------
__global__ void __launch_bounds__(256, 2)
k_attn(const unsigned short* __restrict__ Qr, const unsigned short* __restrict__ Kr,
       const unsigned short* __restrict__ Vt, unsigned short* __restrict__ ctx) {
  __shared__ unsigned short Ks[2][64 * 128];   // [buf][kv][d] swizzled, 16KB each
  __shared__ unsigned short Vs[2][128 * 64];   // [buf][d][kv] swizzled, 16KB each
  const int bid = blockIdx.x;
  const int kv = bid & 7;
  const int hd = kv * 4 + ((bid >> 3) & 3);
  const int qb = 15 - (bid >> 5);
  const int q0 = qb * 128;
  const int tid = threadIdx.x;
  const int l = tid & 63;
  const int w = tid >> 6;
  const int i5 = l & 31;
  const int h  = l >> 5;
  const int qg = q0 + w * 16 + (i5 & 15) + (i5 >> 4) * 64;

  const char* Kbase = (const char*)(Kr + (size_t)kv * 2048 * 128);
  const char* Vbase = (const char*)(Vt + (size_t)kv * 128 * 2048);

  bf16x8 qf[8];
#pragma unroll
  for (int s = 0; s < 8; ++s)
    qf[s] = *reinterpret_cast<const bf16x8*>(
        Qr + ((size_t)hd * 2048 + qg) * 128 + s * 16 + h * 8);

  f32x16 po[4] = {};
  float mrow = -1e30f, lrow = 0.f;

  const int krow = tid >> 4;
  const int kcol = (tid & 15) * 16;
  const int vrow = tid >> 3;
  const int vcol = (tid & 7) * 16;

#define STAGE_KV(JT, BUF)                                                      \
  {                                                                            \
    _Pragma("unroll")                                                          \
    for (int ii = 0; ii < 4; ++ii) {                                           \
      int row = ii * 16 + krow;                                                \
      gload_lds16(Kbase + (size_t)((JT) * 64 + row) * 256 +                    \
                      (kcol ^ ((row & 7) << 4)),                               \
                  (char*)Ks[BUF] + row * 256 + kcol);                          \
    }                                                                          \
    _Pragma("unroll")                                                          \
    for (int ii = 0; ii < 4; ++ii) {                                           \
      int row = ii * 32 + vrow;                                                \
      gload_lds16(Vbase + (size_t)row * 4096 + (JT) * 128 +                    \
                      (vcol ^ ((row & 7) << 4)),                               \
                  (char*)Vs[BUF] + row * 128 + vcol);                          \
    }                                                                          \
  }

  STAGE_KV(0, 0)

  const int jmax = 2 * qb + 2;
  for (int j = 0; j < jmax; ++j) {
    const int cur = j & 1;
    const int jn = (j + 1 < jmax) ? j + 1 : j;
    STAGE_KV(jn, cur ^ 1)
    asm volatile("s_waitcnt vmcnt(8)" ::: "memory");
    __builtin_amdgcn_sched_barrier(0);
    __builtin_amdgcn_s_barrier();
    __builtin_amdgcn_sched_barrier(0);

    const unsigned short* Kc = Ks[cur];
    const unsigned short* Vc = Vs[cur];

    f32x16 sa[2] = {};
    __builtin_amdgcn_s_setprio(1);
#pragma unroll
    for (int ni = 0; ni < 2; ++ni) {
      const int row = ni * 32 + i5;
      const int swz = (row & 7) << 4;
#pragma unroll
      for (int s = 0; s < 8; ++s) {
        bf16x8 kf = *reinterpret_cast<const bf16x8*>(
            (const char*)Kc + ((row * 256 + s * 32 + h * 16) ^ swz));
        sa[ni] = MFMA32(kf, qf[s], sa[ni]);
      }
    }
    __builtin_amdgcn_s_setprio(0);

    if (j >= 2 * qb) {
#pragma unroll
      for (int ni = 0; ni < 2; ++ni) {
        const int kvb = j * 64 + ni * 32 + 4 * h;
#pragma unroll
        for (int r = 0; r < 16; ++r) {
          int kvg = kvb + (r & 3) + 8 * (r >> 2);
          if (kvg > qg) sa[ni][r] = -__builtin_inff();
        }
      }
    }

    float pmax = sa[0][0];
#pragma unroll
    for (int r = 1; r < 16; ++r) pmax = fmaxf(pmax, sa[0][r]);
#pragma unroll
    for (int r = 0; r < 16; ++r) pmax = fmaxf(pmax, sa[1][r]);
    pmax = fmaxf(pmax, __shfl_xor(pmax, 32));

    if (!__all(pmax <= mrow + 8.0f)) {
      float mnew = fmaxf(mrow, pmax);
      float sf = __expf(mrow - mnew);
#pragma unroll
      for (int d = 0; d < 4; ++d)
#pragma unroll
        for (int r = 0; r < 16; ++r) po[d][r] *= sf;
      lrow *= sf;
      mrow = mnew;
    }

    float rs = 0.f;
#pragma unroll
    for (int ni = 0; ni < 2; ++ni)
#pragma unroll
      for (int r = 0; r < 16; ++r) {
        float p = __expf(sa[ni][r] - mrow);
        sa[ni][r] = p;
        rs += p;
      }
    rs += __shfl_xor(rs, 32);
    lrow += rs;

    bf16x8 pfrag[4];
#pragma unroll
    for (int ni = 0; ni < 2; ++ni) {
      unsigned wd[8];
#pragma unroll
      for (int c = 0; c < 4; ++c)
#pragma unroll
        for (int ii = 0; ii < 2; ++ii)
          wd[c * 2 + ii] = (unsigned)f2b(sa[ni][4 * c + 2 * ii]) |
                           ((unsigned)f2b(sa[ni][4 * c + 2 * ii + 1]) << 16);
#pragma unroll
      for (int k2 = 0; k2 < 2; ++k2) {
        unsigned e0 = wd[(2 * k2) * 2 + 0], e1 = wd[(2 * k2) * 2 + 1];
        unsigned o0 = wd[(2 * k2 + 1) * 2 + 0], o1 = wd[(2 * k2 + 1) * 2 + 1];
        unsigned pe0 = (unsigned)__shfl_xor((int)e0, 32);
        unsigned pe1 = (unsigned)__shfl_xor((int)e1, 32);
        unsigned po0 = (unsigned)__shfl_xor((int)o0, 32);
        unsigned po1 = (unsigned)__shfl_xor((int)o1, 32);
        union { unsigned u[4]; bf16x8 v; } uu;
        uu.u[0] = h ? po0 : e0;
        uu.u[1] = h ? po1 : e1;
        uu.u[2] = h ? o0 : pe0;
        uu.u[3] = h ? o1 : pe1;
        pfrag[ni * 2 + k2] = uu.v;
      }
    }

    __builtin_amdgcn_s_setprio(1);
#pragma unroll
    for (int d = 0; d < 4; ++d) {
      const int row0 = d * 32 + i5;
      const int swz = (row0 & 7) << 4;
#pragma unroll
      for (int ks = 0; ks < 4; ++ks) {
        bf16x8 vf = *reinterpret_cast<const bf16x8*>(
            (const char*)Vc + ((row0 * 128 + ks * 32 + h * 16) ^ swz));
        po[d] = MFMA32(vf, pfrag[ks], po[d]);
      }
    }
    __builtin_amdgcn_s_setprio(0);

    __builtin_amdgcn_sched_barrier(0);
    __builtin_amdgcn_s_barrier();
    __builtin_amdgcn_sched_barrier(0);
  }
#undef STAGE_KV

  const float inv = 1.0f / lrow;
#pragma unroll
  for (int d = 0; d < 4; ++d)
#pragma unroll
    for (int c = 0; c < 4; ++c) {
      ushort4 st;
      st.x = f2b(po[d][4 * c + 0] * inv);
      st.y = f2b(po[d][4 * c + 1] * inv);
      st.z = f2b(po[d][4 * c + 2] * inv);
      st.w = f2b(po[d][4 * c + 3] * inv);
      *reinterpret_cast<ushort4*>(
          ctx + (size_t)qg * 4096 + hd * 128 + d * 32 + 8 * c + 4 * h) = st;
    }
}

// ---------- launch ----------
extern "C" void kernel_launch(void* const* d_in, const int* in_sizes, int n_in,
                              void* d_out, int out_size, void* d_ws, size_t ws_size,
                              hipStream_t stream) {
  const float* X    = (const float*)d_in[0];
  const float* cosb = (const float*)d_in[2];
  const float* sinb = (const float*)d_in[3];
  const float* Wq   = (const float*)d_in[4];
  const float* Wk   = (const float*)d_in[5];
  const float* Wv   = (const float*)d_in[6];
  const float* Wo   = (const float*)d_in[7];

  char* ws = (char*)d_ws;
  unsigned short* WT   = (unsigned short*)(ws + 0);           // 6144x4096 bf16 (later: WoT)
  unsigned short* Xb   = (unsigned short*)(ws + 50331648ull); // 2048x4096 bf16
  unsigned short* Cpre = (unsigned short*)(ws + 67108864ull); // 2048x6144 bf16 (later: ctx)
  unsigned short* Qr   = (unsigned short*)(ws + 92274688ull); // 32x2048x128 bf16
  unsigned short* Kr   = (unsigned short*)(ws + 109051904ull);// 8x2048x128 bf16
  unsigned short* Vt   = (unsigned short*)(ws + 113246208ull);// 8x128x2048 bf16
  unsigned short* ctx  = Cpre;

  k_transpose_qkv<<<dim3(64, 96), 256, 0, stream>>>(Wq, Wk, Wv, WT);
  k_f32_to_bf16<<<8192, 256, 0, stream>>>(X, Xb);

  // fused QKV projection: 128^2 tiles, BK=64 double-buffered, XCD-swizzled (768)
  k_gemm<false><<<768, 256, 0, stream>>>(Xb, WT, Cpre, 2048, 6144, 4096);

  k_rope<<<dim3(2048, 20), 256, 0, stream>>>(Cpre, cosb, sinb, Qr, Kr);
  k_transpose_v<<<dim3(32, 2, 8), 256, 0, stream>>>(Cpre, Vt);

  k_transpose_f32_bf16<<<dim3(64, 64), 256, 0, stream>>>(Wo, WT, 4096, 4096);

  k_attn<<<512, 256, 0, stream>>>(Qr, Kr, Vt, ctx);

  // out projection: BK=64 double-buffered, XCD-swizzled (512)
  k_gemm<true><<<512, 256, 0, stream>>>(ctx, WT, d_out, 2048, 4096, 4096);
}

// Round 13
// 355.444 us; speedup vs baseline: 1.0094x; 1.0094x over previous
//
#include <hip/hip_runtime.h>
#include <hip/hip_bf16.h>
#include <stdint.h>
#include <stddef.h>

// ---------- types ----------
typedef __attribute__((ext_vector_type(8))) short bf16x8;          // 8 bf16 in 4 VGPRs
typedef __attribute__((ext_vector_type(8))) unsigned short u16x8;  // 16B vector
typedef __attribute__((ext_vector_type(4))) float f32x4;
typedef __attribute__((ext_vector_type(16))) float f32x16;

#define MFMA16(a, b, c) __builtin_amdgcn_mfma_f32_16x16x32_bf16((a), (b), (c), 0, 0, 0)
#define MFMA32(a, b, c) __builtin_amdgcn_mfma_f32_32x32x16_bf16((a), (b), (c), 0, 0, 0)

__device__ __forceinline__ unsigned short f2b(float f) {  // f32 -> bf16 RNE
  union { float f; unsigned u; } v; v.f = f;
  unsigned r = v.u + 0x7fffu + ((v.u >> 16) & 1u);
  return (unsigned short)(r >> 16);
}
__device__ __forceinline__ float b2f(unsigned short h) {
  union { unsigned u; float f; } v; v.u = ((unsigned)h) << 16;
  return v.f;
}

__device__ __forceinline__ void gload_lds16(const void* g, void* l) {
  __builtin_amdgcn_global_load_lds((const __attribute__((address_space(1))) void*)g,
                                   (__attribute__((address_space(3))) void*)l, 16, 0, 0);
}

// ---------- fused Wq/Wk/Wv transpose+convert -> WT[n][k] (n<6144, k<4096) ----------
__global__ void k_transpose_qkv(const float* __restrict__ Wq, const float* __restrict__ Wk,
                                const float* __restrict__ Wv, unsigned short* __restrict__ out) {
  __shared__ float tile[64][65];
  const int kb = blockIdx.x * 64;
  const int nbg = blockIdx.y * 64;          // fused output row block (0..6143)
  const float* src; int srcN, nb;
  if (nbg < 4096)      { src = Wq; srcN = 4096; nb = nbg; }
  else if (nbg < 5120) { src = Wk; srcN = 1024; nb = nbg - 4096; }
  else                 { src = Wv; srcN = 1024; nb = nbg - 5120; }
  const int t = threadIdx.x;
  const int c4 = (t & 15) * 4;
  const int rr = t >> 4;
#pragma unroll
  for (int i = 0; i < 4; ++i) {
    int r = rr + i * 16;
    float4 v = *reinterpret_cast<const float4*>(src + (size_t)(kb + r) * srcN + nb + c4);
    tile[r][c4 + 0] = v.x; tile[r][c4 + 1] = v.y;
    tile[r][c4 + 2] = v.z; tile[r][c4 + 3] = v.w;
  }
  __syncthreads();
#pragma unroll
  for (int i = 0; i < 4; ++i) {
    int n = rr + i * 16;
    ushort4 w;
    w.x = f2b(tile[c4 + 0][n]); w.y = f2b(tile[c4 + 1][n]);
    w.z = f2b(tile[c4 + 2][n]); w.w = f2b(tile[c4 + 3][n]);
    *reinterpret_cast<ushort4*>(out + (size_t)(nbg + n) * 4096 + kb + c4) = w;
  }
}

// ---------- transpose + convert f32 (K x N) -> bf16 (N x K) ----------
__global__ void k_transpose_f32_bf16(const float* __restrict__ in,
                                     unsigned short* __restrict__ out,
                                     int K, int N) {
  __shared__ float tile[64][65];
  const int kb = blockIdx.x * 64;
  const int nb = blockIdx.y * 64;
  const int t = threadIdx.x;
  const int c4 = (t & 15) * 4;
  const int rr = t >> 4;
#pragma unroll
  for (int i = 0; i < 4; ++i) {
    int r = rr + i * 16;
    float4 v = *reinterpret_cast<const float4*>(in + (size_t)(kb + r) * N + nb + c4);
    tile[r][c4 + 0] = v.x; tile[r][c4 + 1] = v.y;
    tile[r][c4 + 2] = v.z; tile[r][c4 + 3] = v.w;
  }
  __syncthreads();
#pragma unroll
  for (int i = 0; i < 4; ++i) {
    int n = rr + i * 16;
    ushort4 w;
    w.x = f2b(tile[c4 + 0][n]); w.y = f2b(tile[c4 + 1][n]);
    w.z = f2b(tile[c4 + 2][n]); w.w = f2b(tile[c4 + 3][n]);
    *reinterpret_cast<ushort4*>(out + (size_t)(nb + n) * K + kb + c4) = w;
  }
}

// ---------- elementwise f32 -> bf16 ----------
__global__ void k_f32_to_bf16(const float* __restrict__ in, unsigned short* __restrict__ out) {
  size_t i = ((size_t)blockIdx.x * blockDim.x + threadIdx.x) * 4;
  float4 v = *reinterpret_cast<const float4*>(in + i);
  ushort4 w; w.x = f2b(v.x); w.y = f2b(v.y); w.z = f2b(v.z); w.w = f2b(v.w);
  *reinterpret_cast<ushort4*>(out + i) = w;
}

// ---------- GEMM v4: R11 base (BK=64, swizzled, 2-barrier) + B-only double-buffer ----------
// LDS 48KB keeps 3 blocks/CU (R12's 64KB dbuf lost co-residency: FETCH +71%, Mfma 45->29).
// Ledger: prologue B(0); iter t issues A(t) then B(t+1)->buf^1; vmcnt(4) flushes
// B(t)+A(t), keeps B(t+1)'s 4 loads in flight across the MFMA phase.
template <bool OUT_F32>
__global__ void __launch_bounds__(256, 2)
k_gemm(const unsigned short* __restrict__ A, const unsigned short* __restrict__ Bt,
       void* __restrict__ C, int M, int N, int K) {
  __shared__ unsigned short As[128 * 64];
  __shared__ unsigned short Bs[2][128 * 64];
  const int nbm = M >> 7;
  const int per = ((M >> 7) * (N >> 7)) >> 3;
  const int wg  = (blockIdx.x & 7) * per + (blockIdx.x >> 3);
  const int m0 = (wg % nbm) * 128;
  const int n0 = (wg / nbm) * 128;
  const int tid = threadIdx.x;
  const int lane = tid & 63;
  const int w = tid >> 6;
  const int wr = w >> 1, wc = w & 1;
  const int cl = lane & 15, rg = lane >> 4;

  f32x4 acc[4][4] = {};

#define GSTAGE_A(T)                                                            \
  { _Pragma("unroll")                                                          \
    for (int i = 0; i < 4; ++i) {                                              \
      int c = i * 256 + tid;                                                   \
      int row = c >> 3;                                                        \
      int sc = ((c & 7) * 8) ^ ((row & 7) * 8);                                \
      gload_lds16(A + (size_t)(m0 + row) * K + (size_t)(T) * 64 + sc,          \
                  As + c * 8); } }

#define GSTAGE_B(T, BUF)                                                       \
  { _Pragma("unroll")                                                          \
    for (int i = 0; i < 4; ++i) {                                              \
      int c = i * 256 + tid;                                                   \
      int row = c >> 3;                                                        \
      int sc = ((c & 7) * 8) ^ ((row & 7) * 8);                                \
      gload_lds16(Bt + (size_t)(n0 + row) * K + (size_t)(T) * 64 + sc,         \
                  Bs[BUF] + c * 8); } }

  // prologue: B tile 0 -> buf 0 (4 loads in flight)
  GSTAGE_B(0, 0)

  const int nt = K >> 6;
  for (int t = 0; t < nt; ++t) {
    const int cur = t & 1;
    const int tn = (t + 1 < nt) ? t + 1 : t;   // clamp keeps vmcnt count uniform
    GSTAGE_A(t)                 // current A tile (4 loads)
    GSTAGE_B(tn, cur ^ 1)       // next B tile (4 loads, stay in flight)
    // gate: B(t)+A(t) (8 oldest) landed; B(t+1)'s 4 remain outstanding
    asm volatile("s_waitcnt vmcnt(4)" ::: "memory");
    __builtin_amdgcn_sched_barrier(0);
    __builtin_amdgcn_s_barrier();
    __builtin_amdgcn_sched_barrier(0);

    bf16x8 a[4][2], b[4][2];
#pragma unroll
    for (int mi = 0; mi < 4; ++mi) {
      int row = wr * 64 + mi * 16 + cl;
      int swz = (row & 7) << 4;   // byte XOR
#pragma unroll
      for (int ks = 0; ks < 2; ++ks)
        a[mi][ks] = *reinterpret_cast<const bf16x8*>(
            (const char*)As + ((row * 128 + (ks * 32 + rg * 8) * 2) ^ swz));
    }
#pragma unroll
    for (int ni = 0; ni < 4; ++ni) {
      int row = wc * 64 + ni * 16 + cl;
      int swz = (row & 7) << 4;
#pragma unroll
      for (int ks = 0; ks < 2; ++ks)
        b[ni][ks] = *reinterpret_cast<const bf16x8*>(
            (const char*)Bs[cur] + ((row * 128 + (ks * 32 + rg * 8) * 2) ^ swz));
    }
    __builtin_amdgcn_s_setprio(1);
#pragma unroll
    for (int ks = 0; ks < 2; ++ks)
#pragma unroll
      for (int mi = 0; mi < 4; ++mi)
#pragma unroll
        for (int ni = 0; ni < 4; ++ni)
          acc[mi][ni] = MFMA16(a[mi][ks], b[ni][ks], acc[mi][ni]);
    __builtin_amdgcn_s_setprio(0);

    // end barrier: all waves done reading As/Bs[cur] before next iter restages
    __builtin_amdgcn_sched_barrier(0);
    __builtin_amdgcn_s_barrier();
    __builtin_amdgcn_sched_barrier(0);
  }
  asm volatile("s_waitcnt vmcnt(0)" ::: "memory");
#undef GSTAGE_A
#undef GSTAGE_B

#pragma unroll
  for (int mi = 0; mi < 4; ++mi)
#pragma unroll
    for (int ni = 0; ni < 4; ++ni) {
      int row = m0 + wr * 64 + mi * 16 + rg * 4;
      int col = n0 + wc * 64 + ni * 16 + cl;
#pragma unroll
      for (int r = 0; r < 4; ++r) {
        float v = acc[mi][ni][r];
        if (OUT_F32) ((float*)C)[(size_t)(row + r) * N + col] = v;
        else         ((unsigned short*)C)[(size_t)(row + r) * N + col] = f2b(v);
      }
    }
}

// ---------- RoPE + reshape ----------
__global__ void k_rope(const unsigned short* __restrict__ Cpre,
                       const float* __restrict__ cosb, const float* __restrict__ sinb,
                       unsigned short* __restrict__ Qr, unsigned short* __restrict__ Kr) {
  const int s = blockIdx.x;
  const int hh = blockIdx.y * 2 + (threadIdx.x >> 7);
  const int d = threadIdx.x & 127;
  const int col = (hh < 32) ? hh * 128 + d : 4096 + (hh - 32) * 128 + d;
  float t = b2f(Cpre[(size_t)s * 6144 + col]);
  const int dp = (d < 64) ? d + 64 : d - 64;
  float tp = b2f(Cpre[(size_t)s * 6144 + (col - d + dp)]);
  float rot = (d < 64) ? -tp : tp;
  float o = t * cosb[s * 128 + d] + rot * sinb[s * 128 + d];
  if (hh < 32) {
    Qr[((size_t)hh * 2048 + s) * 128 + d] = f2b(o * 0.08838834764831845f);
  } else {
    Kr[((size_t)(hh - 32) * 2048 + s) * 128 + d] = f2b(o);
  }
}

// ---------- V transpose: Cpre[S, 5120 + kv*128 + d] -> Vt[KV, DH, S] ----------
__global__ void k_transpose_v(const unsigned short* __restrict__ Cpre,
                              unsigned short* __restrict__ Vt) {
  __shared__ unsigned short tile[64][72];
  const int sb = blockIdx.x * 64;
  const int db = blockIdx.y * 64;
  const int kv = blockIdx.z;
  const int t = threadIdx.x;
#pragma unroll
  for (int i = 0; i < 2; ++i) {
    int sl = i * 32 + (t >> 3);
    int d8 = (t & 7) * 8;
    const unsigned short* src = Cpre + (size_t)(sb + sl) * 6144 + 5120 + kv * 128 + db + d8;
    ushort4 v0 = *reinterpret_cast<const ushort4*>(src);
    ushort4 v1 = *reinterpret_cast<const ushort4*>(src + 4);
    *reinterpret_cast<ushort4*>(&tile[sl][d8]) = v0;
    *reinterpret_cast<ushort4*>(&tile[sl][d8 + 4]) = v1;
  }
  __syncthreads();
#pragma unroll
  for (int i = 0; i < 2; ++i) {
    int dl = i * 32 + (t >> 3);
    int s8 = (t & 7) * 8;
    ushort4 w0, w1;
    w0.x = tile[s8 + 0][dl]; w0.y = tile[s8 + 1][dl]; w0.z = tile[s8 + 2][dl]; w0.w = tile[s8 + 3][dl];
    w1.x = tile[s8 + 4][dl]; w1.y = tile[s8 + 5][dl]; w1.z = tile[s8 + 6][dl]; w1.w = tile[s8 + 7][dl];
    unsigned short* dst = Vt + ((size_t)kv * 128 + db + dl) * 2048 + sb + s8;
    *reinterpret_cast<ushort4*>(dst) = w0;
    *reinterpret_cast<ushort4*>(dst + 4) = w1;
  }
}

// ---------- fused causal GQA flash attention (R10 known-good) ----------
__global__ void __launch_bounds__(256, 2)
k_attn(const unsigned short* __restrict__ Qr, const unsigned short* __restrict__ Kr,
       const unsigned short* __restrict__ Vt, unsigned short* __restrict__ ctx) {
  __shared__ unsigned short Ks[2][64 * 128];   // [buf][kv][d] swizzled, 16KB each
  __shared__ unsigned short Vs[2][128 * 64];   // [buf][d][kv] swizzled, 16KB each
  const int bid = blockIdx.x;
  const int kv = bid & 7;
  const int hd = kv * 4 + ((bid >> 3) & 3);
  const int qb = 15 - (bid >> 5);
  const int q0 = qb * 128;
  const int tid = threadIdx.x;
  const int l = tid & 63;
  const int w = tid >> 6;
  const int i5 = l & 31;
  const int h  = l >> 5;
  const int qg = q0 + w * 16 + (i5 & 15) + (i5 >> 4) * 64;

  const char* Kbase = (const char*)(Kr + (size_t)kv * 2048 * 128);
  const char* Vbase = (const char*)(Vt + (size_t)kv * 128 * 2048);

  bf16x8 qf[8];
#pragma unroll
  for (int s = 0; s < 8; ++s)
    qf[s] = *reinterpret_cast<const bf16x8*>(
        Qr + ((size_t)hd * 2048 + qg) * 128 + s * 16 + h * 8);

  f32x16 po[4] = {};
  float mrow = -1e30f, lrow = 0.f;

  const int krow = tid >> 4;
  const int kcol = (tid & 15) * 16;
  const int vrow = tid >> 3;
  const int vcol = (tid & 7) * 16;

#define STAGE_KV(JT, BUF)                                                      \
  {                                                                            \
    _Pragma("unroll")                                                          \
    for (int ii = 0; ii < 4; ++ii) {                                           \
      int row = ii * 16 + krow;                                                \
      gload_lds16(Kbase + (size_t)((JT) * 64 + row) * 256 +                    \
                      (kcol ^ ((row & 7) << 4)),                               \
                  (char*)Ks[BUF] + row * 256 + kcol);                          \
    }                                                                          \
    _Pragma("unroll")                                                          \
    for (int ii = 0; ii < 4; ++ii) {                                           \
      int row = ii * 32 + vrow;                                                \
      gload_lds16(Vbase + (size_t)row * 4096 + (JT) * 128 +                    \
                      (vcol ^ ((row & 7) << 4)),                               \
                  (char*)Vs[BUF] + row * 128 + vcol);                          \
    }                                                                          \
  }

  STAGE_KV(0, 0)

  const int jmax = 2 * qb + 2;
  for (int j = 0; j < jmax; ++j) {
    const int cur = j & 1;
    const int jn = (j + 1 < jmax) ? j + 1 : j;
    STAGE_KV(jn, cur ^ 1)
    asm volatile("s_waitcnt vmcnt(8)" ::: "memory");
    __builtin_amdgcn_sched_barrier(0);
    __builtin_amdgcn_s_barrier();
    __builtin_amdgcn_sched_barrier(0);

    const unsigned short* Kc = Ks[cur];
    const unsigned short* Vc = Vs[cur];

    f32x16 sa[2] = {};
    __builtin_amdgcn_s_setprio(1);
#pragma unroll
    for (int ni = 0; ni < 2; ++ni) {
      const int row = ni * 32 + i5;
      const int swz = (row & 7) << 4;
#pragma unroll
      for (int s = 0; s < 8; ++s) {
        bf16x8 kf = *reinterpret_cast<const bf16x8*>(
            (const char*)Kc + ((row * 256 + s * 32 + h * 16) ^ swz));
        sa[ni] = MFMA32(kf, qf[s], sa[ni]);
      }
    }
    __builtin_amdgcn_s_setprio(0);

    if (j >= 2 * qb) {
#pragma unroll
      for (int ni = 0; ni < 2; ++ni) {
        const int kvb = j * 64 + ni * 32 + 4 * h;
#pragma unroll
        for (int r = 0; r < 16; ++r) {
          int kvg = kvb + (r & 3) + 8 * (r >> 2);
          if (kvg > qg) sa[ni][r] = -__builtin_inff();
        }
      }
    }

    float pmax = sa[0][0];
#pragma unroll
    for (int r = 1; r < 16; ++r) pmax = fmaxf(pmax, sa[0][r]);
#pragma unroll
    for (int r = 0; r < 16; ++r) pmax = fmaxf(pmax, sa[1][r]);
    pmax = fmaxf(pmax, __shfl_xor(pmax, 32));

    if (!__all(pmax <= mrow + 8.0f)) {
      float mnew = fmaxf(mrow, pmax);
      float sf = __expf(mrow - mnew);
#pragma unroll
      for (int d = 0; d < 4; ++d)
#pragma unroll
        for (int r = 0; r < 16; ++r) po[d][r] *= sf;
      lrow *= sf;
      mrow = mnew;
    }

    float rs = 0.f;
#pragma unroll
    for (int ni = 0; ni < 2; ++ni)
#pragma unroll
      for (int r = 0; r < 16; ++r) {
        float p = __expf(sa[ni][r] - mrow);
        sa[ni][r] = p;
        rs += p;
      }
    rs += __shfl_xor(rs, 32);
    lrow += rs;

    bf16x8 pfrag[4];
#pragma unroll
    for (int ni = 0; ni < 2; ++ni) {
      unsigned wd[8];
#pragma unroll
      for (int c = 0; c < 4; ++c)
#pragma unroll
        for (int ii = 0; ii < 2; ++ii)
          wd[c * 2 + ii] = (unsigned)f2b(sa[ni][4 * c + 2 * ii]) |
                           ((unsigned)f2b(sa[ni][4 * c + 2 * ii + 1]) << 16);
#pragma unroll
      for (int k2 = 0; k2 < 2; ++k2) {
        unsigned e0 = wd[(2 * k2) * 2 + 0], e1 = wd[(2 * k2) * 2 + 1];
        unsigned o0 = wd[(2 * k2 + 1) * 2 + 0], o1 = wd[(2 * k2 + 1) * 2 + 1];
        unsigned pe0 = (unsigned)__shfl_xor((int)e0, 32);
        unsigned pe1 = (unsigned)__shfl_xor((int)e1, 32);
        unsigned po0 = (unsigned)__shfl_xor((int)o0, 32);
        unsigned po1 = (unsigned)__shfl_xor((int)o1, 32);
        union { unsigned u[4]; bf16x8 v; } uu;
        uu.u[0] = h ? po0 : e0;
        uu.u[1] = h ? po1 : e1;
        uu.u[2] = h ? o0 : pe0;
        uu.u[3] = h ? o1 : pe1;
        pfrag[ni * 2 + k2] = uu.v;
      }
    }

    __builtin_amdgcn_s_setprio(1);
#pragma unroll
    for (int d = 0; d < 4; ++d) {
      const int row0 = d * 32 + i5;
      const int swz = (row0 & 7) << 4;
#pragma unroll
      for (int ks = 0; ks < 4; ++ks) {
        bf16x8 vf = *reinterpret_cast<const bf16x8*>(
            (const char*)Vc + ((row0 * 128 + ks * 32 + h * 16) ^ swz));
        po[d] = MFMA32(vf, pfrag[ks], po[d]);
      }
    }
    __builtin_amdgcn_s_setprio(0);

    __builtin_amdgcn_sched_barrier(0);
    __builtin_amdgcn_s_barrier();
    __builtin_amdgcn_sched_barrier(0);
  }
#undef STAGE_KV

  const float inv = 1.0f / lrow;
#pragma unroll
  for (int d = 0; d < 4; ++d)
#pragma unroll
    for (int c = 0; c < 4; ++c) {
      ushort4 st;
      st.x = f2b(po[d][4 * c + 0] * inv);
      st.y = f2b(po[d][4 * c + 1] * inv);
      st.z = f2b(po[d][4 * c + 2] * inv);
      st.w = f2b(po[d][4 * c + 3] * inv);
      *reinterpret_cast<ushort4*>(
          ctx + (size_t)qg * 4096 + hd * 128 + d * 32 + 8 * c + 4 * h) = st;
    }
}

// ---------- launch ----------
extern "C" void kernel_launch(void* const* d_in, const int* in_sizes, int n_in,
                              void* d_out, int out_size, void* d_ws, size_t ws_size,
                              hipStream_t stream) {
  const float* X    = (const float*)d_in[0];
  const float* cosb = (const float*)d_in[2];
  const float* sinb = (const float*)d_in[3];
  const float* Wq   = (const float*)d_in[4];
  const float* Wk   = (const float*)d_in[5];
  const float* Wv   = (const float*)d_in[6];
  const float* Wo   = (const float*)d_in[7];

  char* ws = (char*)d_ws;
  unsigned short* WT   = (unsigned short*)(ws + 0);           // 6144x4096 bf16 (later: WoT)
  unsigned short* Xb   = (unsigned short*)(ws + 50331648ull); // 2048x4096 bf16
  unsigned short* Cpre = (unsigned short*)(ws + 67108864ull); // 2048x6144 bf16 (later: ctx)
  unsigned short* Qr   = (unsigned short*)(ws + 92274688ull); // 32x2048x128 bf16
  unsigned short* Kr   = (unsigned short*)(ws + 109051904ull);// 8x2048x128 bf16
  unsigned short* Vt   = (unsigned short*)(ws + 113246208ull);// 8x128x2048 bf16
  unsigned short* ctx  = Cpre;

  k_transpose_qkv<<<dim3(64, 96), 256, 0, stream>>>(Wq, Wk, Wv, WT);
  k_f32_to_bf16<<<8192, 256, 0, stream>>>(X, Xb);

  // fused QKV projection: 128^2 tiles, BK=64, B-dbuf, XCD-swizzled (768)
  k_gemm<false><<<768, 256, 0, stream>>>(Xb, WT, Cpre, 2048, 6144, 4096);

  k_rope<<<dim3(2048, 20), 256, 0, stream>>>(Cpre, cosb, sinb, Qr, Kr);
  k_transpose_v<<<dim3(32, 2, 8), 256, 0, stream>>>(Cpre, Vt);

  k_transpose_f32_bf16<<<dim3(64, 64), 256, 0, stream>>>(Wo, WT, 4096, 4096);

  k_attn<<<512, 256, 0, stream>>>(Qr, Kr, Vt, ctx);

  // out projection: BK=64, B-dbuf, XCD-swizzled (512)
  k_gemm<true><<<512, 256, 0, stream>>>(ctx, WT, d_out, 2048, 4096, 4096);
}

// Round 14
// 322.942 us; speedup vs baseline: 1.1110x; 1.1006x over previous
//
#include <hip/hip_runtime.h>
#include <hip/hip_bf16.h>
#include <stdint.h>
#include <stddef.h>

// ---------- types ----------
typedef __attribute__((ext_vector_type(8))) short bf16x8;          // 8 bf16 in 4 VGPRs
typedef __attribute__((ext_vector_type(8))) unsigned short u16x8;  // 16B vector
typedef __attribute__((ext_vector_type(4))) float f32x4;
typedef __attribute__((ext_vector_type(16))) float f32x16;

#define MFMA16(a, b, c) __builtin_amdgcn_mfma_f32_16x16x32_bf16((a), (b), (c), 0, 0, 0)
#define MFMA32(a, b, c) __builtin_amdgcn_mfma_f32_32x32x16_bf16((a), (b), (c), 0, 0, 0)

__device__ __forceinline__ unsigned short f2b(float f) {  // f32 -> bf16 RNE
  union { float f; unsigned u; } v; v.f = f;
  unsigned r = v.u + 0x7fffu + ((v.u >> 16) & 1u);
  return (unsigned short)(r >> 16);
}
__device__ __forceinline__ float b2f(unsigned short h) {
  union { unsigned u; float f; } v; v.u = ((unsigned)h) << 16;
  return v.f;
}

__device__ __forceinline__ void gload_lds16(const void* g, void* l) {
  __builtin_amdgcn_global_load_lds((const __attribute__((address_space(1))) void*)g,
                                   (__attribute__((address_space(3))) void*)l, 16, 0, 0);
}

// ---------- fused Wq/Wk/Wv transpose+convert -> WT[n][k] (n<6144, k<4096) ----------
__global__ void k_transpose_qkv(const float* __restrict__ Wq, const float* __restrict__ Wk,
                                const float* __restrict__ Wv, unsigned short* __restrict__ out) {
  __shared__ float tile[64][65];
  const int kb = blockIdx.x * 64;
  const int nbg = blockIdx.y * 64;          // fused output row block (0..6143)
  const float* src; int srcN, nb;
  if (nbg < 4096)      { src = Wq; srcN = 4096; nb = nbg; }
  else if (nbg < 5120) { src = Wk; srcN = 1024; nb = nbg - 4096; }
  else                 { src = Wv; srcN = 1024; nb = nbg - 5120; }
  const int t = threadIdx.x;
  const int c4 = (t & 15) * 4;
  const int rr = t >> 4;
#pragma unroll
  for (int i = 0; i < 4; ++i) {
    int r = rr + i * 16;
    float4 v = *reinterpret_cast<const float4*>(src + (size_t)(kb + r) * srcN + nb + c4);
    tile[r][c4 + 0] = v.x; tile[r][c4 + 1] = v.y;
    tile[r][c4 + 2] = v.z; tile[r][c4 + 3] = v.w;
  }
  __syncthreads();
#pragma unroll
  for (int i = 0; i < 4; ++i) {
    int n = rr + i * 16;
    ushort4 w;
    w.x = f2b(tile[c4 + 0][n]); w.y = f2b(tile[c4 + 1][n]);
    w.z = f2b(tile[c4 + 2][n]); w.w = f2b(tile[c4 + 3][n]);
    *reinterpret_cast<ushort4*>(out + (size_t)(nbg + n) * 4096 + kb + c4) = w;
  }
}

// ---------- transpose + convert f32 (K x N) -> bf16 (N x K) ----------
__global__ void k_transpose_f32_bf16(const float* __restrict__ in,
                                     unsigned short* __restrict__ out,
                                     int K, int N) {
  __shared__ float tile[64][65];
  const int kb = blockIdx.x * 64;
  const int nb = blockIdx.y * 64;
  const int t = threadIdx.x;
  const int c4 = (t & 15) * 4;
  const int rr = t >> 4;
#pragma unroll
  for (int i = 0; i < 4; ++i) {
    int r = rr + i * 16;
    float4 v = *reinterpret_cast<const float4*>(in + (size_t)(kb + r) * N + nb + c4);
    tile[r][c4 + 0] = v.x; tile[r][c4 + 1] = v.y;
    tile[r][c4 + 2] = v.z; tile[r][c4 + 3] = v.w;
  }
  __syncthreads();
#pragma unroll
  for (int i = 0; i < 4; ++i) {
    int n = rr + i * 16;
    ushort4 w;
    w.x = f2b(tile[c4 + 0][n]); w.y = f2b(tile[c4 + 1][n]);
    w.z = f2b(tile[c4 + 2][n]); w.w = f2b(tile[c4 + 3][n]);
    *reinterpret_cast<ushort4*>(out + (size_t)(nb + n) * K + kb + c4) = w;
  }
}

// ---------- elementwise f32 -> bf16 ----------
__global__ void k_f32_to_bf16(const float* __restrict__ in, unsigned short* __restrict__ out) {
  size_t i = ((size_t)blockIdx.x * blockDim.x + threadIdx.x) * 4;
  float4 v = *reinterpret_cast<const float4*>(in + i);
  ushort4 w; w.x = f2b(v.x); w.y = f2b(v.y); w.z = f2b(v.z); w.w = f2b(v.w);
  *reinterpret_cast<ushort4*>(out + i) = w;
}

// ---------- GEMM (R11 verified-best): BK=64, swizzled single-buffer, 2-barrier,
// T1 XCD swizzle. Bank conflicts 0, MfmaUtil ~45%, FETCH at ideal (~91MB QKV).
// Dbuf variants (R12 64KB, R13 48KB B-only) both regressed: co-residency loss
// + L2 B-panel thrash (FETCH +71%). This is the verified optimum of the family.
template <bool OUT_F32>
__global__ void __launch_bounds__(256, 2)
k_gemm(const unsigned short* __restrict__ A, const unsigned short* __restrict__ Bt,
       void* __restrict__ C, int M, int N, int K) {
  __shared__ unsigned short As[128 * 64];
  __shared__ unsigned short Bs[128 * 64];
  const int nbm = M >> 7;
  const int per = ((M >> 7) * (N >> 7)) >> 3;
  const int wg  = (blockIdx.x & 7) * per + (blockIdx.x >> 3);
  const int m0 = (wg % nbm) * 128;
  const int n0 = (wg / nbm) * 128;
  const int tid = threadIdx.x;
  const int lane = tid & 63;
  const int w = tid >> 6;
  const int wr = w >> 1, wc = w & 1;
  const int cl = lane & 15, rg = lane >> 4;

  f32x4 acc[4][4] = {};

  for (int k0 = 0; k0 < K; k0 += 64) {
    // stage 128x64 A and B: 4 gloads each per thread; src col pre-swizzled
#pragma unroll
    for (int i = 0; i < 4; ++i) {
      int c = i * 256 + tid;          // 0..1023
      int row = c >> 3;
      int sc = ((c & 7) * 8) ^ ((row & 7) * 8);   // elems; ^(row&7)<<4 bytes
      gload_lds16(A + (size_t)(m0 + row) * K + k0 + sc, As + c * 8);
    }
#pragma unroll
    for (int i = 0; i < 4; ++i) {
      int c = i * 256 + tid;
      int row = c >> 3;
      int sc = ((c & 7) * 8) ^ ((row & 7) * 8);
      gload_lds16(Bt + (size_t)(n0 + row) * K + k0 + sc, Bs + c * 8);
    }
    __syncthreads();
    bf16x8 a[4][2], b[4][2];
#pragma unroll
    for (int mi = 0; mi < 4; ++mi) {
      int row = wr * 64 + mi * 16 + cl;
      int swz = (row & 7) << 4;   // byte XOR
#pragma unroll
      for (int ks = 0; ks < 2; ++ks)
        a[mi][ks] = *reinterpret_cast<const bf16x8*>(
            (const char*)As + ((row * 128 + (ks * 32 + rg * 8) * 2) ^ swz));
    }
#pragma unroll
    for (int ni = 0; ni < 4; ++ni) {
      int row = wc * 64 + ni * 16 + cl;
      int swz = (row & 7) << 4;
#pragma unroll
      for (int ks = 0; ks < 2; ++ks)
        b[ni][ks] = *reinterpret_cast<const bf16x8*>(
            (const char*)Bs + ((row * 128 + (ks * 32 + rg * 8) * 2) ^ swz));
    }
#pragma unroll
    for (int ks = 0; ks < 2; ++ks)
#pragma unroll
      for (int mi = 0; mi < 4; ++mi)
#pragma unroll
        for (int ni = 0; ni < 4; ++ni)
          acc[mi][ni] = MFMA16(a[mi][ks], b[ni][ks], acc[mi][ni]);
    __syncthreads();
  }
#pragma unroll
  for (int mi = 0; mi < 4; ++mi)
#pragma unroll
    for (int ni = 0; ni < 4; ++ni) {
      int row = m0 + wr * 64 + mi * 16 + rg * 4;
      int col = n0 + wc * 64 + ni * 16 + cl;
#pragma unroll
      for (int r = 0; r < 4; ++r) {
        float v = acc[mi][ni][r];
        if (OUT_F32) ((float*)C)[(size_t)(row + r) * N + col] = v;
        else         ((unsigned short*)C)[(size_t)(row + r) * N + col] = f2b(v);
      }
    }
}

// ---------- RoPE + reshape ----------
__global__ void k_rope(const unsigned short* __restrict__ Cpre,
                       const float* __restrict__ cosb, const float* __restrict__ sinb,
                       unsigned short* __restrict__ Qr, unsigned short* __restrict__ Kr) {
  const int s = blockIdx.x;
  const int hh = blockIdx.y * 2 + (threadIdx.x >> 7);
  const int d = threadIdx.x & 127;
  const int col = (hh < 32) ? hh * 128 + d : 4096 + (hh - 32) * 128 + d;
  float t = b2f(Cpre[(size_t)s * 6144 + col]);
  const int dp = (d < 64) ? d + 64 : d - 64;
  float tp = b2f(Cpre[(size_t)s * 6144 + (col - d + dp)]);
  float rot = (d < 64) ? -tp : tp;
  float o = t * cosb[s * 128 + d] + rot * sinb[s * 128 + d];
  if (hh < 32) {
    Qr[((size_t)hh * 2048 + s) * 128 + d] = f2b(o * 0.08838834764831845f);
  } else {
    Kr[((size_t)(hh - 32) * 2048 + s) * 128 + d] = f2b(o);
  }
}

// ---------- V transpose: Cpre[S, 5120 + kv*128 + d] -> Vt[KV, DH, S] ----------
__global__ void k_transpose_v(const unsigned short* __restrict__ Cpre,
                              unsigned short* __restrict__ Vt) {
  __shared__ unsigned short tile[64][72];
  const int sb = blockIdx.x * 64;
  const int db = blockIdx.y * 64;
  const int kv = blockIdx.z;
  const int t = threadIdx.x;
#pragma unroll
  for (int i = 0; i < 2; ++i) {
    int sl = i * 32 + (t >> 3);
    int d8 = (t & 7) * 8;
    const unsigned short* src = Cpre + (size_t)(sb + sl) * 6144 + 5120 + kv * 128 + db + d8;
    ushort4 v0 = *reinterpret_cast<const ushort4*>(src);
    ushort4 v1 = *reinterpret_cast<const ushort4*>(src + 4);
    *reinterpret_cast<ushort4*>(&tile[sl][d8]) = v0;
    *reinterpret_cast<ushort4*>(&tile[sl][d8 + 4]) = v1;
  }
  __syncthreads();
#pragma unroll
  for (int i = 0; i < 2; ++i) {
    int dl = i * 32 + (t >> 3);
    int s8 = (t & 7) * 8;
    ushort4 w0, w1;
    w0.x = tile[s8 + 0][dl]; w0.y = tile[s8 + 1][dl]; w0.z = tile[s8 + 2][dl]; w0.w = tile[s8 + 3][dl];
    w1.x = tile[s8 + 4][dl]; w1.y = tile[s8 + 5][dl]; w1.z = tile[s8 + 6][dl]; w1.w = tile[s8 + 7][dl];
    unsigned short* dst = Vt + ((size_t)kv * 128 + db + dl) * 2048 + sb + s8;
    *reinterpret_cast<ushort4*>(dst) = w0;
    *reinterpret_cast<ushort4*>(dst + 4) = w1;
  }
}

// ---------- fused causal GQA flash attention (R10 known-good) ----------
__global__ void __launch_bounds__(256, 2)
k_attn(const unsigned short* __restrict__ Qr, const unsigned short* __restrict__ Kr,
       const unsigned short* __restrict__ Vt, unsigned short* __restrict__ ctx) {
  __shared__ unsigned short Ks[2][64 * 128];   // [buf][kv][d] swizzled, 16KB each
  __shared__ unsigned short Vs[2][128 * 64];   // [buf][d][kv] swizzled, 16KB each
  const int bid = blockIdx.x;
  const int kv = bid & 7;
  const int hd = kv * 4 + ((bid >> 3) & 3);
  const int qb = 15 - (bid >> 5);
  const int q0 = qb * 128;
  const int tid = threadIdx.x;
  const int l = tid & 63;
  const int w = tid >> 6;
  const int i5 = l & 31;
  const int h  = l >> 5;
  const int qg = q0 + w * 16 + (i5 & 15) + (i5 >> 4) * 64;

  const char* Kbase = (const char*)(Kr + (size_t)kv * 2048 * 128);
  const char* Vbase = (const char*)(Vt + (size_t)kv * 128 * 2048);

  bf16x8 qf[8];
#pragma unroll
  for (int s = 0; s < 8; ++s)
    qf[s] = *reinterpret_cast<const bf16x8*>(
        Qr + ((size_t)hd * 2048 + qg) * 128 + s * 16 + h * 8);

  f32x16 po[4] = {};
  float mrow = -1e30f, lrow = 0.f;

  const int krow = tid >> 4;
  const int kcol = (tid & 15) * 16;
  const int vrow = tid >> 3;
  const int vcol = (tid & 7) * 16;

#define STAGE_KV(JT, BUF)                                                      \
  {                                                                            \
    _Pragma("unroll")                                                          \
    for (int ii = 0; ii < 4; ++ii) {                                           \
      int row = ii * 16 + krow;                                                \
      gload_lds16(Kbase + (size_t)((JT) * 64 + row) * 256 +                    \
                      (kcol ^ ((row & 7) << 4)),                               \
                  (char*)Ks[BUF] + row * 256 + kcol);                          \
    }                                                                          \
    _Pragma("unroll")                                                          \
    for (int ii = 0; ii < 4; ++ii) {                                           \
      int row = ii * 32 + vrow;                                                \
      gload_lds16(Vbase + (size_t)row * 4096 + (JT) * 128 +                    \
                      (vcol ^ ((row & 7) << 4)),                               \
                  (char*)Vs[BUF] + row * 128 + vcol);                          \
    }                                                                          \
  }

  STAGE_KV(0, 0)

  const int jmax = 2 * qb + 2;
  for (int j = 0; j < jmax; ++j) {
    const int cur = j & 1;
    const int jn = (j + 1 < jmax) ? j + 1 : j;
    STAGE_KV(jn, cur ^ 1)
    asm volatile("s_waitcnt vmcnt(8)" ::: "memory");
    __builtin_amdgcn_sched_barrier(0);
    __builtin_amdgcn_s_barrier();
    __builtin_amdgcn_sched_barrier(0);

    const unsigned short* Kc = Ks[cur];
    const unsigned short* Vc = Vs[cur];

    f32x16 sa[2] = {};
    __builtin_amdgcn_s_setprio(1);
#pragma unroll
    for (int ni = 0; ni < 2; ++ni) {
      const int row = ni * 32 + i5;
      const int swz = (row & 7) << 4;
#pragma unroll
      for (int s = 0; s < 8; ++s) {
        bf16x8 kf = *reinterpret_cast<const bf16x8*>(
            (const char*)Kc + ((row * 256 + s * 32 + h * 16) ^ swz));
        sa[ni] = MFMA32(kf, qf[s], sa[ni]);
      }
    }
    __builtin_amdgcn_s_setprio(0);

    if (j >= 2 * qb) {
#pragma unroll
      for (int ni = 0; ni < 2; ++ni) {
        const int kvb = j * 64 + ni * 32 + 4 * h;
#pragma unroll
        for (int r = 0; r < 16; ++r) {
          int kvg = kvb + (r & 3) + 8 * (r >> 2);
          if (kvg > qg) sa[ni][r] = -__builtin_inff();
        }
      }
    }

    float pmax = sa[0][0];
#pragma unroll
    for (int r = 1; r < 16; ++r) pmax = fmaxf(pmax, sa[0][r]);
#pragma unroll
    for (int r = 0; r < 16; ++r) pmax = fmaxf(pmax, sa[1][r]);
    pmax = fmaxf(pmax, __shfl_xor(pmax, 32));

    if (!__all(pmax <= mrow + 8.0f)) {
      float mnew = fmaxf(mrow, pmax);
      float sf = __expf(mrow - mnew);
#pragma unroll
      for (int d = 0; d < 4; ++d)
#pragma unroll
        for (int r = 0; r < 16; ++r) po[d][r] *= sf;
      lrow *= sf;
      mrow = mnew;
    }

    float rs = 0.f;
#pragma unroll
    for (int ni = 0; ni < 2; ++ni)
#pragma unroll
      for (int r = 0; r < 16; ++r) {
        float p = __expf(sa[ni][r] - mrow);
        sa[ni][r] = p;
        rs += p;
      }
    rs += __shfl_xor(rs, 32);
    lrow += rs;

    bf16x8 pfrag[4];
#pragma unroll
    for (int ni = 0; ni < 2; ++ni) {
      unsigned wd[8];
#pragma unroll
      for (int c = 0; c < 4; ++c)
#pragma unroll
        for (int ii = 0; ii < 2; ++ii)
          wd[c * 2 + ii] = (unsigned)f2b(sa[ni][4 * c + 2 * ii]) |
                           ((unsigned)f2b(sa[ni][4 * c + 2 * ii + 1]) << 16);
#pragma unroll
      for (int k2 = 0; k2 < 2; ++k2) {
        unsigned e0 = wd[(2 * k2) * 2 + 0], e1 = wd[(2 * k2) * 2 + 1];
        unsigned o0 = wd[(2 * k2 + 1) * 2 + 0], o1 = wd[(2 * k2 + 1) * 2 + 1];
        unsigned pe0 = (unsigned)__shfl_xor((int)e0, 32);
        unsigned pe1 = (unsigned)__shfl_xor((int)e1, 32);
        unsigned po0 = (unsigned)__shfl_xor((int)o0, 32);
        unsigned po1 = (unsigned)__shfl_xor((int)o1, 32);
        union { unsigned u[4]; bf16x8 v; } uu;
        uu.u[0] = h ? po0 : e0;
        uu.u[1] = h ? po1 : e1;
        uu.u[2] = h ? o0 : pe0;
        uu.u[3] = h ? o1 : pe1;
        pfrag[ni * 2 + k2] = uu.v;
      }
    }

    __builtin_amdgcn_s_setprio(1);
#pragma unroll
    for (int d = 0; d < 4; ++d) {
      const int row0 = d * 32 + i5;
      const int swz = (row0 & 7) << 4;
#pragma unroll
      for (int ks = 0; ks < 4; ++ks) {
        bf16x8 vf = *reinterpret_cast<const bf16x8*>(
            (const char*)Vc + ((row0 * 128 + ks * 32 + h * 16) ^ swz));
        po[d] = MFMA32(vf, pfrag[ks], po[d]);
      }
    }
    __builtin_amdgcn_s_setprio(0);

    __builtin_amdgcn_sched_barrier(0);
    __builtin_amdgcn_s_barrier();
    __builtin_amdgcn_sched_barrier(0);
  }
#undef STAGE_KV

  const float inv = 1.0f / lrow;
#pragma unroll
  for (int d = 0; d < 4; ++d)
#pragma unroll
    for (int c = 0; c < 4; ++c) {
      ushort4 st;
      st.x = f2b(po[d][4 * c + 0] * inv);
      st.y = f2b(po[d][4 * c + 1] * inv);
      st.z = f2b(po[d][4 * c + 2] * inv);
      st.w = f2b(po[d][4 * c + 3] * inv);
      *reinterpret_cast<ushort4*>(
          ctx + (size_t)qg * 4096 + hd * 128 + d * 32 + 8 * c + 4 * h) = st;
    }
}

// ---------- launch ----------
extern "C" void kernel_launch(void* const* d_in, const int* in_sizes, int n_in,
                              void* d_out, int out_size, void* d_ws, size_t ws_size,
                              hipStream_t stream) {
  const float* X    = (const float*)d_in[0];
  const float* cosb = (const float*)d_in[2];
  const float* sinb = (const float*)d_in[3];
  const float* Wq   = (const float*)d_in[4];
  const float* Wk   = (const float*)d_in[5];
  const float* Wv   = (const float*)d_in[6];
  const float* Wo   = (const float*)d_in[7];

  char* ws = (char*)d_ws;
  unsigned short* WT   = (unsigned short*)(ws + 0);           // 6144x4096 bf16 (later: WoT)
  unsigned short* Xb   = (unsigned short*)(ws + 50331648ull); // 2048x4096 bf16
  unsigned short* Cpre = (unsigned short*)(ws + 67108864ull); // 2048x6144 bf16 (later: ctx)
  unsigned short* Qr   = (unsigned short*)(ws + 92274688ull); // 32x2048x128 bf16
  unsigned short* Kr   = (unsigned short*)(ws + 109051904ull);// 8x2048x128 bf16
  unsigned short* Vt   = (unsigned short*)(ws + 113246208ull);// 8x128x2048 bf16
  unsigned short* ctx  = Cpre;

  k_transpose_qkv<<<dim3(64, 96), 256, 0, stream>>>(Wq, Wk, Wv, WT);
  k_f32_to_bf16<<<8192, 256, 0, stream>>>(X, Xb);

  // fused QKV projection: 128^2 tiles, BK=64, XCD-swizzled 1D grid (768)
  k_gemm<false><<<768, 256, 0, stream>>>(Xb, WT, Cpre, 2048, 6144, 4096);

  k_rope<<<dim3(2048, 20), 256, 0, stream>>>(Cpre, cosb, sinb, Qr, Kr);
  k_transpose_v<<<dim3(32, 2, 8), 256, 0, stream>>>(Cpre, Vt);

  k_transpose_f32_bf16<<<dim3(64, 64), 256, 0, stream>>>(Wo, WT, 4096, 4096);

  k_attn<<<512, 256, 0, stream>>>(Qr, Kr, Vt, ctx);

  // out projection: BK=64, XCD-swizzled 1D grid (512)
  k_gemm<true><<<512, 256, 0, stream>>>(ctx, WT, d_out, 2048, 4096, 4096);
}